// Round 16
// baseline (92.415 us; speedup 1.0000x reference)
//
#include <hip/hip_runtime.h>
#include <hip/hip_bf16.h>

#define B_   8
#define S_   1024
#define D_   128
#define NH_  8
#define HD_  16
#define E_   4
#define HFF_ 512
#define NTOK (B_*S_)

typedef unsigned short ushort_t;
typedef __attribute__((ext_vector_type(8))) short bf16x8;
typedef __attribute__((ext_vector_type(4))) float f32x4;
typedef __attribute__((ext_vector_type(4))) _Float16 f16x4;

static __device__ __forceinline__ ushort_t f2bf(float f) {
    union { float f; unsigned u; } v; v.f = f;
    unsigned r = v.u + 0x7FFF + ((v.u >> 16) & 1);   // RNE
    return (ushort_t)(r >> 16);
}
static __device__ __forceinline__ float bf2f(ushort_t u) {
    union { unsigned u; float f; } v; v.u = ((unsigned)u) << 16;
    return v.f;
}

// ---------------------------------------------------------------------------
// prep (weights only): bf16 transposed layouts.
// ---------------------------------------------------------------------------
__global__ __launch_bounds__(256)
void prep(const float* __restrict__ Wqkv, const float* __restrict__ Wo,
          const float* __restrict__ W1, const float* __restrict__ W2,
          ushort_t* __restrict__ Wqkv_t, ushort_t* __restrict__ Wo_t,
          ushort_t* __restrict__ W1t, ushort_t* __restrict__ W2t)
{
    const int seg = blockIdx.y;
    const int i = blockIdx.x * 256 + threadIdx.x;
    if (seg == 0) {
        if (i < D_ * 3 * D_) {
            int r = i / (3 * D_), c = i % (3 * D_);
            Wqkv_t[c * D_ + r] = f2bf(Wqkv[i]);
        }
    } else if (seg == 1) {
        if (i < D_ * D_) {
            int r = i >> 7, c = i & 127;
            Wo_t[c * D_ + r] = f2bf(Wo[i]);
        }
    } else if (seg == 2) {                // W1 -> [4][512][128]
        int e = i >> 16, rem = i & 65535, r = rem >> 9, c = rem & 511;
        W1t[e * 65536 + c * 128 + r] = f2bf(W1[i]);
    } else {                              // W2 -> [4][128][512]
        int e = i >> 16, rem = i & 65535, k2 = rem >> 7, dd = rem & 127;
        W2t[e * 65536 + dd * 512 + k2] = f2bf(W2[i]);
    }
}

// ---------------------------------------------------------------------------
// QKV GEMM: 128x128 tile, 4 waves (2x2). blockIdx.y = part (0=Q,1=K,2=V).
// A read from f32 x directly (in-register convert).
// ---------------------------------------------------------------------------
__global__ __launch_bounds__(256)
void gemm_qkv(const float* __restrict__ x, const ushort_t* __restrict__ Bt,
              const float* __restrict__ bias,
              _Float16* __restrict__ pq, _Float16* __restrict__ pk,
              _Float16* __restrict__ pv)
{
    __shared__ __align__(16) ushort_t As[4][128][8];
    __shared__ __align__(16) ushort_t Bs[4][128][8];
    const int bm = blockIdx.x * 128;
    const int bn = blockIdx.y * 128;
    const int part = blockIdx.y;
    const int tid = threadIdx.x;
    const int l = tid & 63, wv = tid >> 6;
    const int lc = l & 15, lg = l >> 4;
    const int wr = wv >> 1, wc = wv & 1;
    const int K = D_;

    f32x4 acc[4][4] = {};

    const int srow = tid & 127, sch = tid >> 7;
    const float*    ap = x  + (size_t)(bm + srow) * K + sch * 8;
    const ushort_t* bp = Bt + (size_t)(bn + srow) * K + sch * 8;

    for (int k0 = 0; k0 < K; k0 += 32) {
        #pragma unroll
        for (int half = 0; half < 2; half++) {
            float4 v0 = *(const float4*)(ap + k0 + half * 16);
            float4 v1 = *(const float4*)(ap + k0 + half * 16 + 4);
            bf16x8 pk8;
            pk8[0] = (short)f2bf(v0.x); pk8[1] = (short)f2bf(v0.y);
            pk8[2] = (short)f2bf(v0.z); pk8[3] = (short)f2bf(v0.w);
            pk8[4] = (short)f2bf(v1.x); pk8[5] = (short)f2bf(v1.y);
            pk8[6] = (short)f2bf(v1.z); pk8[7] = (short)f2bf(v1.w);
            *(bf16x8*)As[sch + half * 2][srow] = pk8;
        }
        *(bf16x8*)Bs[sch][srow]     = *(const bf16x8*)(bp + k0);
        *(bf16x8*)Bs[sch + 2][srow] = *(const bf16x8*)(bp + k0 + 16);
        __syncthreads();
        bf16x8 af[4], bfr[4];
        #pragma unroll
        for (int f = 0; f < 4; f++) {
            af[f]  = *(const bf16x8*)As[lg][wr * 64 + f * 16 + lc];
            bfr[f] = *(const bf16x8*)Bs[lg][wc * 64 + f * 16 + lc];
        }
        #pragma unroll
        for (int fm = 0; fm < 4; fm++)
            #pragma unroll
            for (int fn = 0; fn < 4; fn++)
                acc[fm][fn] = __builtin_amdgcn_mfma_f32_16x16x32_bf16(
                    af[fm], bfr[fn], acc[fm][fn], 0, 0, 0);
        __syncthreads();
    }

    #pragma unroll
    for (int fm = 0; fm < 4; fm++) {
        #pragma unroll
        for (int fn = 0; fn < 4; fn++) {
            const int col = bn + wc * 64 + fn * 16 + lc;
            const int hh = (col >> 4) & 7, dd = col & 15;
            const int row0 = bm + wr * 64 + fm * 16 + lg * 4;
            const int b = row0 >> 10, s0 = row0 & 1023;
            const size_t bh = (size_t)(b * NH_ + hh);
            const float bcol = bias[col];
            if (part == 2) {
                f16x4 vv;
                #pragma unroll
                for (int rr = 0; rr < 4; rr++)
                    vv[rr] = (_Float16)(acc[fm][fn][rr] + bcol);
                *(f16x4*)&pv[(bh << 14) + (dd << 10) + s0] = vv;
            } else {
                const float sc = (part == 0) ? 0.36067376022224085f : 1.f;
                _Float16* dst = (part == 0) ? pq : pk;
                #pragma unroll
                for (int rr = 0; rr < 4; rr++)
                    dst[(bh * 1024 + s0 + rr) * HD_ + dd] =
                        (_Float16)((acc[fm][fn][rr] + bcol) * sc);
            }
        }
    }
}

// ---------------------------------------------------------------------------
// Out-proj: BM=64, BN=128, 128 blocks; t f32; fused norm1 stats -> pstatA.
// ---------------------------------------------------------------------------
__global__ __launch_bounds__(256)
void gemm_out(const ushort_t* __restrict__ attno, const ushort_t* __restrict__ Wo_t,
              const float* __restrict__ bo, const float* __restrict__ x,
              float* __restrict__ t, float* __restrict__ pstatA)
{
    __shared__ __align__(16) ushort_t As[4][64][8];
    __shared__ __align__(16) ushort_t Bs[4][128][8];
    __shared__ float2 sred[4][128];
    const int tok0 = blockIdx.x * 64;
    const int tid = threadIdx.x;
    const int l = tid & 63, wv = tid >> 6;
    const int lc = l & 15, lg = l >> 4;

    f32x4 acc[8] = {};

    const int arow = tid & 63, akc = tid >> 6;
    const int bn = tid & 127, bj = tid >> 7;
    const ushort_t* ap = attno + (size_t)(tok0 + arow) * D_ + akc * 8;
    const ushort_t* bp = Wo_t + (size_t)bn * D_ + bj * 16;

    for (int k0 = 0; k0 < 128; k0 += 32) {
        *(bf16x8*)As[akc][arow]     = *(const bf16x8*)(ap + k0);
        *(bf16x8*)Bs[bj * 2][bn]     = *(const bf16x8*)(bp + k0);
        *(bf16x8*)Bs[bj * 2 + 1][bn] = *(const bf16x8*)(bp + k0 + 8);
        __syncthreads();
        bf16x8 af = *(const bf16x8*)As[lg][wv * 16 + lc];
        #pragma unroll
        for (int fn = 0; fn < 8; fn++) {
            bf16x8 bf = *(const bf16x8*)Bs[lg][fn * 16 + lc];
            acc[fn] = __builtin_amdgcn_mfma_f32_16x16x32_bf16(af, bf, acc[fn], 0, 0, 0);
        }
        __syncthreads();
    }

    const int bb = tok0 >> 10, c16 = (tok0 >> 6) & 15;
    #pragma unroll
    for (int fn = 0; fn < 8; fn++) {
        const int col = fn * 16 + lc;
        float s = 0.f, q = 0.f;
        #pragma unroll
        for (int rr = 0; rr < 4; rr++) {
            const int row = wv * 16 + lg * 4 + rr;
            const size_t off = (size_t)(tok0 + row) * D_ + col;
            float v = acc[fn][rr] + bo[col] + x[off];
            t[off] = v;
            s += v; q += v * v;
        }
        s += __shfl_xor(s, 16); q += __shfl_xor(q, 16);
        s += __shfl_xor(s, 32); q += __shfl_xor(q, 32);
        if (l < 16) sred[wv][col] = make_float2(s, q);
    }
    __syncthreads();
    if (tid < 128) {
        float2 a0 = sred[0][tid], a1 = sred[1][tid], a2 = sred[2][tid], a3 = sred[3][tid];
        ((float2*)pstatA)[(bb * 16 + c16) * D_ + tid] =
            make_float2(a0.x + a1.x + a2.x + a3.x, a0.y + a1.y + a2.y + a3.y);
    }
}

// ---------------------------------------------------------------------------
// Fully fused MoE: norm1 (from pstatA) + f32 gating + 2 GEMMs, per block
// 64 tokens x 1 expert, grid (128, 4). c-loop fully unrolled so the compiler
// can hoist next-chunk weight loads under the current chunk's MFMAs.
// ---------------------------------------------------------------------------
__global__ __launch_bounds__(256)
void moe_fused(const float* __restrict__ t, const float* __restrict__ pstatA,
               const float* __restrict__ n1w, const float* __restrict__ n1b,
               const float* __restrict__ wg,
               const ushort_t* __restrict__ W1t, const ushort_t* __restrict__ W2t,
               const float* __restrict__ b1, const float* __restrict__ b2,
               ushort_t* __restrict__ ypartb)
{
    __shared__ __align__(16) ushort_t As[16][64][8];
    __shared__ __align__(16) ushort_t HS[16][64][8];
    __shared__ float2 sst[128];
    __shared__ float4 glog[4][64];
    __shared__ float garr[64];
    const int tok0 = blockIdx.x * 64, e = blockIdx.y;
    const int tid = threadIdx.x;
    const int l = tid & 63, wv = tid >> 6;
    const int lc = l & 15, lg = l >> 4;
    const int bb = tok0 >> 10;

    if (tid < 128) {
        float sum = 0.f, sq = 0.f;
        const float2* pp = (const float2*)pstatA;
        #pragma unroll 4
        for (int c = 0; c < 16; c++) {
            float2 v = pp[(bb * 16 + c) * D_ + tid];
            sum += v.x; sq += v.y;
        }
        const float invS = 1.f / (float)S_;
        float mu = sum * invS;
        float var = sq * invS - mu * mu;
        sst[tid] = make_float2(mu, rsqrtf(var + 1e-5f));
    }
    __syncthreads();

    {
        const int row = tid & 63, part = tid >> 6;
        const float* src = t + (size_t)(tok0 + row) * D_ + part * 32;
        float4 aa = make_float4(0.f, 0.f, 0.f, 0.f);
        #pragma unroll
        for (int j = 0; j < 4; j++) {
            bf16x8 pk8;
            #pragma unroll
            for (int half = 0; half < 2; half++) {
                float4 v = *(const float4*)(src + j * 8 + half * 4);
                const int db = part * 32 + j * 8 + half * 4;
                float hv[4] = {v.x, v.y, v.z, v.w};
                #pragma unroll
                for (int c = 0; c < 4; c++) {
                    float2 s = sst[db + c];
                    hv[c] = (hv[c] - s.x) * s.y * n1w[db + c] + n1b[db + c];
                    float4 wj = ((const float4*)wg)[db + c];
                    aa.x += hv[c] * wj.x; aa.y += hv[c] * wj.y;
                    aa.z += hv[c] * wj.z; aa.w += hv[c] * wj.w;
                    pk8[half * 4 + c] = (short)f2bf(hv[c]);
                }
            }
            *(bf16x8*)As[part * 4 + j][row] = pk8;
        }
        glog[part][row] = aa;
    }
    __syncthreads();
    if (tid < 64) {
        float4 a0 = glog[0][tid], a1 = glog[1][tid], a2 = glog[2][tid], a3 = glog[3][tid];
        float lv[4] = {a0.x + a1.x + a2.x + a3.x, a0.y + a1.y + a2.y + a3.y,
                       a0.z + a1.z + a2.z + a3.z, a0.w + a1.w + a2.w + a3.w};
        int i0 = 0; float mm0 = lv[0];
        #pragma unroll
        for (int k = 1; k < 4; k++) if (lv[k] > mm0) { mm0 = lv[k]; i0 = k; }
        int i1 = -1; float mm1 = -1e30f;
        #pragma unroll
        for (int k = 0; k < 4; k++) {
            if (k == i0) continue;
            if (lv[k] > mm1) { mm1 = lv[k]; i1 = k; }
        }
        float te = __expf(mm1 - mm0);
        float g0 = 1.f / (1.f + te);
        float g1 = te * g0;
        garr[tid] = (e == i0) ? g0 : (e == i1) ? g1 : 0.f;
    }
    __syncthreads();

    const ushort_t* W1e = W1t + (size_t)e * HFF_ * D_;
    const ushort_t* W2e = W2t + (size_t)e * D_ * HFF_;
    const int col0 = wv * 32 + lc;

    f32x4 acc2[4][2] = {};

    #pragma unroll
    for (int c = 0; c < 4; c++) {
        bf16x8 w1f[4][2], w2f[4][2];
        #pragma unroll
        for (int ks = 0; ks < 4; ks++)
            #pragma unroll
            for (int fn = 0; fn < 2; fn++) {
                w1f[ks][fn] = *(const bf16x8*)&W1e[(size_t)(c * 128 + col0 + fn * 16) * D_ + ks * 32 + lg * 8];
                w2f[ks][fn] = *(const bf16x8*)&W2e[(size_t)(col0 + fn * 16) * HFF_ + c * 128 + ks * 32 + lg * 8];
            }
        f32x4 acc1[4][2] = {};
        #pragma unroll
        for (int ks = 0; ks < 4; ks++) {
            bf16x8 af[4];
            #pragma unroll
            for (int f = 0; f < 4; f++) af[f] = *(const bf16x8*)As[ks * 4 + lg][f * 16 + lc];
            #pragma unroll
            for (int fm = 0; fm < 4; fm++)
                #pragma unroll
                for (int fn = 0; fn < 2; fn++)
                    acc1[fm][fn] = __builtin_amdgcn_mfma_f32_16x16x32_bf16(
                        af[fm], w1f[ks][fn], acc1[fm][fn], 0, 0, 0);
        }
        __syncthreads();
        #pragma unroll
        for (int fm = 0; fm < 4; fm++)
            #pragma unroll
            for (int fn = 0; fn < 2; fn++)
                #pragma unroll
                for (int rr = 0; rr < 4; rr++) {
                    const int row = fm * 16 + lg * 4 + rr;
                    const int col = wv * 32 + fn * 16 + lc;
                    float v = fmaxf(acc1[fm][fn][rr] + b1[e * HFF_ + c * 128 + col], 0.f);
                    HS[col >> 3][row][col & 7] = f2bf(v);
                }
        __syncthreads();
        #pragma unroll
        for (int ks2 = 0; ks2 < 4; ks2++) {
            bf16x8 af[4];
            #pragma unroll
            for (int f = 0; f < 4; f++) af[f] = *(const bf16x8*)HS[ks2 * 4 + lg][f * 16 + lc];
            #pragma unroll
            for (int fm = 0; fm < 4; fm++)
                #pragma unroll
                for (int fn = 0; fn < 2; fn++)
                    acc2[fm][fn] = __builtin_amdgcn_mfma_f32_16x16x32_bf16(
                        af[fm], w2f[ks2][fn], acc2[fm][fn], 0, 0, 0);
        }
    }

    #pragma unroll
    for (int fm = 0; fm < 4; fm++)
        #pragma unroll
        for (int rr = 0; rr < 4; rr++) {
            const int row = fm * 16 + lg * 4 + rr;
            const float g = garr[row];
            #pragma unroll
            for (int fn = 0; fn < 2; fn++) {
                const int d = wv * 32 + fn * 16 + lc;
                ypartb[((size_t)e * NTOK + tok0 + row) * D_ + d] =
                    f2bf(g * (acc2[fm][fn][rr] + b2[e * D_ + d]));
            }
        }
}

// ---------------------------------------------------------------------------
// MFMA flash attention, LDS-staged K/V, 8 waves x 32 q rows (2 qtiles).
// grid (B*NH, 4), 512 threads. Each 64KB K/V stage now serves 256 q rows;
// V fragment shared across both qtiles.
// ---------------------------------------------------------------------------
#define KT_STR 20
#define VT_STR 136

__global__ __launch_bounds__(512)
void attn_mfma(const _Float16* __restrict__ Qb, const _Float16* __restrict__ Kb,
               const _Float16* __restrict__ Vt, ushort_t* __restrict__ attno)
{
    __shared__ __align__(16) _Float16 KT[2][128 * KT_STR];
    __shared__ __align__(16) _Float16 VTs[2][16 * VT_STR];
    const int bh = blockIdx.x;
    const int tid = threadIdx.x;
    const int wv = tid >> 6;
    const int l  = tid & 63;
    const int r = l & 15, g = l >> 4;
    const int g4 = g * 4;
    const int q0 = blockIdx.y * 256 + wv * 32;

    const _Float16* qp = Qb + ((size_t)bh << 14);
    const _Float16* kp = Kb + ((size_t)bh << 14);
    const _Float16* vp = Vt + ((size_t)bh << 14);

    f16x4 qf0 = *(const f16x4*)&qp[(q0 + r) * HD_ + g4];
    f16x4 qf1 = *(const f16x4*)&qp[(q0 + 16 + r) * HD_ + g4];

    const int krow = tid >> 2, kq = tid & 3;
    const int kofs = krow * KT_STR + kq * 4;
    const _Float16* kg = kp + krow * HD_ + kq * 4;
    const int vrow = tid >> 5, vsc = tid & 31;
    const int vofs = vrow * VT_STR + vsc * 4;
    const _Float16* vg = vp + vrow * 1024 + vsc * 4;

    const int kbase = r * KT_STR + g4;
    const int vbase = r * VT_STR + g4;

    f32x4 o0 = {}, o1 = {};
    float lp0 = 0.f, lp1 = 0.f;

    {
        *(f16x4*)&KT[0][kofs]  = *(const f16x4*)kg;
        *(f16x4*)&VTs[0][vofs] = *(const f16x4*)vg;
    }
    __syncthreads();

    int cur = 0;
    #pragma unroll 1
    for (int t = 0; t < 8; t++) {
        f16x4 kr, vr;
        if (t < 7) {
            kr = *(const f16x4*)(kg + (t + 1) * 2048);
            vr = *(const f16x4*)(vg + (t + 1) * 128);
        }
        const _Float16* KTc = KT[cur];
        const _Float16* VTc = VTs[cur];
        #pragma unroll
        for (int kt = 0; kt < 8; kt++) {
            f16x4 kf = *(const f16x4*)&KTc[kbase + kt * (16 * KT_STR)];
            f16x4 vf = *(const f16x4*)&VTc[vbase + kt * 16];
            f32x4 z = {};
            f32x4 s0 = __builtin_amdgcn_mfma_f32_16x16x16f16(kf, qf0, z, 0, 0, 0);
            f32x4 s1 = __builtin_amdgcn_mfma_f32_16x16x16f16(kf, qf1, z, 0, 0, 0);
            float p0 = exp2f(s0[0]), p1 = exp2f(s0[1]), p2 = exp2f(s0[2]), p3 = exp2f(s0[3]);
            float p4 = exp2f(s1[0]), p5 = exp2f(s1[1]), p6 = exp2f(s1[2]), p7 = exp2f(s1[3]);
            lp0 += (p0 + p1) + (p2 + p3);
            lp1 += (p4 + p5) + (p6 + p7);
            f16x4 pf0, pf1;
            pf0[0] = (_Float16)p0; pf0[1] = (_Float16)p1;
            pf0[2] = (_Float16)p2; pf0[3] = (_Float16)p3;
            pf1[0] = (_Float16)p4; pf1[1] = (_Float16)p5;
            pf1[2] = (_Float16)p6; pf1[3] = (_Float16)p7;
            o0 = __builtin_amdgcn_mfma_f32_16x16x16f16(vf, pf0, o0, 0, 0, 0);
            o1 = __builtin_amdgcn_mfma_f32_16x16x16f16(vf, pf1, o1, 0, 0, 0);
        }
        if (t < 7) {
            *(f16x4*)&KT[cur ^ 1][kofs]  = kr;
            *(f16x4*)&VTs[cur ^ 1][vofs] = vr;
        }
        __syncthreads();
        cur ^= 1;
    }

    lp0 += __shfl_xor(lp0, 16); lp0 += __shfl_xor(lp0, 32);
    lp1 += __shfl_xor(lp1, 16); lp1 += __shfl_xor(lp1, 32);
    const float inv0 = 1.f / lp0, inv1 = 1.f / lp1;

    const int b = bh >> 3, h = bh & 7;
    ushort4 out0, out1;
    out0.x = f2bf(o0[0] * inv0); out0.y = f2bf(o0[1] * inv0);
    out0.z = f2bf(o0[2] * inv0); out0.w = f2bf(o0[3] * inv0);
    out1.x = f2bf(o1[0] * inv1); out1.y = f2bf(o1[1] * inv1);
    out1.z = f2bf(o1[2] * inv1); out1.w = f2bf(o1[3] * inv1);
    *(ushort4*)&attno[((size_t)(b * S_ + q0 + r)) * D_ + h * HD_ + g4] = out0;
    *(ushort4*)&attno[((size_t)(b * S_ + q0 + 16 + r)) * D_ + h * HD_ + g4] = out1;
}

// ---------------------------------------------------------------------------
// Reduce: yh = norm1(t) + sum_e ypartb[e]; norm1 recomputed inline from
// pstatA. Writes yhb bf16 + norm2 partials -> pstatB. grid (B, 32), 128 thr.
// ---------------------------------------------------------------------------
__global__ __launch_bounds__(128)
void moe_reduce_stats(const ushort_t* __restrict__ ypartb, const float* __restrict__ t,
                      const float* __restrict__ pstatA,
                      const float* __restrict__ n1w, const float* __restrict__ n1b,
                      ushort_t* __restrict__ yhb, float* __restrict__ pstatB)
{
    const int bb = blockIdx.x, chunk = blockIdx.y, d = threadIdx.x;

    float sum0 = 0.f, sq0 = 0.f;
    const float2* pp = (const float2*)pstatA;
    #pragma unroll 4
    for (int c = 0; c < 16; c++) {
        float2 v = pp[(bb * 16 + c) * D_ + d];
        sum0 += v.x; sq0 += v.y;
    }
    const float invS = 1.f / (float)S_;
    const float mu = sum0 * invS;
    const float rstd = rsqrtf(sq0 * invS - mu * mu + 1e-5f);
    const float wd = n1w[d], bd = n1b[d];

    float sum = 0.f, sq = 0.f;
    for (int s = 0; s < 32; s++) {
        const size_t off = ((size_t)bb * 1024 + chunk * 32 + s) * D_ + d;
        float hv = (t[off] - mu) * rstd * wd + bd;
        float v = hv
                + bf2f(ypartb[off])
                + bf2f(ypartb[(size_t)1 * NTOK * D_ + off])
                + bf2f(ypartb[(size_t)2 * NTOK * D_ + off])
                + bf2f(ypartb[(size_t)3 * NTOK * D_ + off]);
        yhb[off] = f2bf(v);
        sum += v; sq += v * v;
    }
    ((float2*)pstatB)[(bb * 32 + chunk) * D_ + d] = make_float2(sum, sq);
}

// ---------------------------------------------------------------------------
// Final norm apply with fused stats combine from pstatB. bf16 in, f32 out.
// ---------------------------------------------------------------------------
__global__ __launch_bounds__(256)
void in_apply_final(const ushort_t* __restrict__ a, const float* __restrict__ pstatB,
                    const float* __restrict__ w, const float* __restrict__ bias,
                    float* __restrict__ outp)
{
    __shared__ float2 sst[128];
    const int tid = threadIdx.x;
    const int bb = (int)((blockIdx.x * 8) >> 10);
    if (tid < 128) {
        float sum = 0.f, sq = 0.f;
        const float2* pp = (const float2*)pstatB;
        #pragma unroll 4
        for (int c = 0; c < 32; c++) {
            float2 v = pp[(bb * 32 + c) * D_ + tid];
            sum += v.x; sq += v.y;
        }
        const float invS = 1.f / (float)S_;
        float mu = sum * invS;
        float var = sq * invS - mu * mu;
        sst[tid] = make_float2(mu, rsqrtf(var + 1e-5f));
    }
    __syncthreads();

    size_t i4 = (size_t)blockIdx.x * 256 + tid;
    int d0 = (tid & 31) * 4;
    ushort4 u = ((const ushort4*)a)[i4];
    float4 v = make_float4(bf2f(u.x), bf2f(u.y), bf2f(u.z), bf2f(u.w));
    float2 s0 = sst[d0 + 0];
    float2 s1 = sst[d0 + 1];
    float2 s2 = sst[d0 + 2];
    float2 s3 = sst[d0 + 3];
    float4 r;
    r.x = (v.x - s0.x) * s0.y * w[d0 + 0] + bias[d0 + 0];
    r.y = (v.y - s1.x) * s1.y * w[d0 + 1] + bias[d0 + 1];
    r.z = (v.z - s2.x) * s2.y * w[d0 + 2] + bias[d0 + 2];
    r.w = (v.w - s3.x) * s3.y * w[d0 + 3] + bias[d0 + 3];
    ((float4*)outp)[i4] = r;
}

// ---------------------------------------------------------------------------
// Launch (7 dispatches)
// ---------------------------------------------------------------------------
extern "C" void kernel_launch(void* const* d_in, const int* in_sizes, int n_in,
                              void* d_out, int out_size, void* d_ws, size_t ws_size,
                              hipStream_t stream)
{
    const float* x    = (const float*)d_in[0];
    const float* Wqkv = (const float*)d_in[1];
    const float* bqkv = (const float*)d_in[2];
    const float* Wo   = (const float*)d_in[3];
    const float* bo   = (const float*)d_in[4];
    const float* n1w  = (const float*)d_in[5];
    const float* n1b  = (const float*)d_in[6];
    const float* n2w  = (const float*)d_in[7];
    const float* n2b  = (const float*)d_in[8];
    const float* wg   = (const float*)d_in[9];
    const float* W1   = (const float*)d_in[10];
    const float* b1   = (const float*)d_in[11];
    const float* W2   = (const float*)d_in[12];
    const float* b2   = (const float*)d_in[13];

    // Workspace layout (~28 MB)
    char* ws = (char*)d_ws;
    _Float16* Qb     = (_Float16*)(ws);                          // [0,2M)
    _Float16* Kb     = (_Float16*)(ws + (2u << 20));             // [2,4M)
    _Float16* Vt     = (_Float16*)(ws + (4u << 20));             // [4,6M)
    ushort_t* attno  = (ushort_t*)(ws + (6u << 20));             // [6,8M)
    float*    t      = (float*)(ws + (8u << 20));                // [8,12M)
    ushort_t* ypartb = (ushort_t*)(ws + (14u << 20));            // [14,22M)
    ushort_t* yhb    = (ushort_t*)(ws + (22u << 20));            // [22,24M)
    char*     wbase  = ws + (26u << 20);
    ushort_t* Wqkv_t = (ushort_t*)(wbase);                       // 96 KB
    ushort_t* Wo_t   = (ushort_t*)(wbase + (128u << 10));        // 32 KB
    ushort_t* W1t    = (ushort_t*)(wbase + (192u << 10));        // 512 KB
    ushort_t* W2t    = (ushort_t*)(wbase + (704u << 10));        // 512 KB
    float*    pstatA = (float*)(wbase + (1216u << 10));          // 128 KB
    float*    pstatB = (float*)(wbase + (1344u << 10));          // 256 KB

    dim3 blk(256);

    prep<<<dim3(1024, 4), blk, 0, stream>>>(Wqkv, Wo, W1, W2,
                                            Wqkv_t, Wo_t, W1t, W2t);
    gemm_qkv<<<dim3(64, 3), blk, 0, stream>>>(x, Wqkv_t, bqkv, Qb, Kb, Vt);
    attn_mfma<<<dim3(64, 4), dim3(512), 0, stream>>>(Qb, Kb, Vt, attno);
    gemm_out<<<dim3(128), blk, 0, stream>>>(attno, Wo_t, bo, x, t, pstatA);
    moe_fused<<<dim3(128, 4), blk, 0, stream>>>(t, pstatA, n1w, n1b, wg,
                                                W1t, W2t, b1, b2, ypartb);
    moe_reduce_stats<<<dim3(B_, 32), dim3(128), 0, stream>>>(ypartb, t, pstatA,
                                                             n1w, n1b, yhb, pstatB);
    in_apply_final<<<dim3(1024), blk, 0, stream>>>(yhb, pstatB, n2w, n2b,
                                                   (float*)d_out);
}

// Round 17
// 89.392 us; speedup vs baseline: 1.0338x; 1.0338x over previous
//
#include <hip/hip_runtime.h>
#include <hip/hip_bf16.h>

#define B_   8
#define S_   1024
#define D_   128
#define NH_  8
#define HD_  16
#define E_   4
#define HFF_ 512
#define NTOK (B_*S_)

typedef unsigned short ushort_t;
typedef __attribute__((ext_vector_type(8))) short bf16x8;
typedef __attribute__((ext_vector_type(4))) float f32x4;
typedef __attribute__((ext_vector_type(4))) _Float16 f16x4;

static __device__ __forceinline__ ushort_t f2bf(float f) {
    union { float f; unsigned u; } v; v.f = f;
    unsigned r = v.u + 0x7FFF + ((v.u >> 16) & 1);   // RNE
    return (ushort_t)(r >> 16);
}
static __device__ __forceinline__ float bf2f(ushort_t u) {
    union { unsigned u; float f; } v; v.u = ((unsigned)u) << 16;
    return v.f;
}

// ---------------------------------------------------------------------------
// prep (weights only): bf16 transposed layouts.
// ---------------------------------------------------------------------------
__global__ __launch_bounds__(256)
void prep(const float* __restrict__ Wqkv, const float* __restrict__ Wo,
          const float* __restrict__ W1, const float* __restrict__ W2,
          ushort_t* __restrict__ Wqkv_t, ushort_t* __restrict__ Wo_t,
          ushort_t* __restrict__ W1t, ushort_t* __restrict__ W2t)
{
    const int seg = blockIdx.y;
    const int i = blockIdx.x * 256 + threadIdx.x;
    if (seg == 0) {
        if (i < D_ * 3 * D_) {
            int r = i / (3 * D_), c = i % (3 * D_);
            Wqkv_t[c * D_ + r] = f2bf(Wqkv[i]);
        }
    } else if (seg == 1) {
        if (i < D_ * D_) {
            int r = i >> 7, c = i & 127;
            Wo_t[c * D_ + r] = f2bf(Wo[i]);
        }
    } else if (seg == 2) {                // W1 -> [4][512][128]
        int e = i >> 16, rem = i & 65535, r = rem >> 9, c = rem & 511;
        W1t[e * 65536 + c * 128 + r] = f2bf(W1[i]);
    } else {                              // W2 -> [4][128][512]
        int e = i >> 16, rem = i & 65535, k2 = rem >> 7, dd = rem & 127;
        W2t[e * 65536 + dd * 512 + k2] = f2bf(W2[i]);
    }
}

// ---------------------------------------------------------------------------
// QKV GEMM: 128x128 tile, 4 waves (2x2). blockIdx.y = part (0=Q,1=K,2=V).
// ---------------------------------------------------------------------------
__global__ __launch_bounds__(256)
void gemm_qkv(const float* __restrict__ x, const ushort_t* __restrict__ Bt,
              const float* __restrict__ bias,
              _Float16* __restrict__ pq, _Float16* __restrict__ pk,
              _Float16* __restrict__ pv)
{
    __shared__ __align__(16) ushort_t As[4][128][8];
    __shared__ __align__(16) ushort_t Bs[4][128][8];
    const int bm = blockIdx.x * 128;
    const int bn = blockIdx.y * 128;
    const int part = blockIdx.y;
    const int tid = threadIdx.x;
    const int l = tid & 63, wv = tid >> 6;
    const int lc = l & 15, lg = l >> 4;
    const int wr = wv >> 1, wc = wv & 1;
    const int K = D_;

    f32x4 acc[4][4] = {};

    const int srow = tid & 127, sch = tid >> 7;
    const float*    ap = x  + (size_t)(bm + srow) * K + sch * 8;
    const ushort_t* bp = Bt + (size_t)(bn + srow) * K + sch * 8;

    for (int k0 = 0; k0 < K; k0 += 32) {
        #pragma unroll
        for (int half = 0; half < 2; half++) {
            float4 v0 = *(const float4*)(ap + k0 + half * 16);
            float4 v1 = *(const float4*)(ap + k0 + half * 16 + 4);
            bf16x8 pk8;
            pk8[0] = (short)f2bf(v0.x); pk8[1] = (short)f2bf(v0.y);
            pk8[2] = (short)f2bf(v0.z); pk8[3] = (short)f2bf(v0.w);
            pk8[4] = (short)f2bf(v1.x); pk8[5] = (short)f2bf(v1.y);
            pk8[6] = (short)f2bf(v1.z); pk8[7] = (short)f2bf(v1.w);
            *(bf16x8*)As[sch + half * 2][srow] = pk8;
        }
        *(bf16x8*)Bs[sch][srow]     = *(const bf16x8*)(bp + k0);
        *(bf16x8*)Bs[sch + 2][srow] = *(const bf16x8*)(bp + k0 + 16);
        __syncthreads();
        bf16x8 af[4], bfr[4];
        #pragma unroll
        for (int f = 0; f < 4; f++) {
            af[f]  = *(const bf16x8*)As[lg][wr * 64 + f * 16 + lc];
            bfr[f] = *(const bf16x8*)Bs[lg][wc * 64 + f * 16 + lc];
        }
        #pragma unroll
        for (int fm = 0; fm < 4; fm++)
            #pragma unroll
            for (int fn = 0; fn < 4; fn++)
                acc[fm][fn] = __builtin_amdgcn_mfma_f32_16x16x32_bf16(
                    af[fm], bfr[fn], acc[fm][fn], 0, 0, 0);
        __syncthreads();
    }

    #pragma unroll
    for (int fm = 0; fm < 4; fm++) {
        #pragma unroll
        for (int fn = 0; fn < 4; fn++) {
            const int col = bn + wc * 64 + fn * 16 + lc;
            const int hh = (col >> 4) & 7, dd = col & 15;
            const int row0 = bm + wr * 64 + fm * 16 + lg * 4;
            const int b = row0 >> 10, s0 = row0 & 1023;
            const size_t bh = (size_t)(b * NH_ + hh);
            const float bcol = bias[col];
            if (part == 2) {
                f16x4 vv;
                #pragma unroll
                for (int rr = 0; rr < 4; rr++)
                    vv[rr] = (_Float16)(acc[fm][fn][rr] + bcol);
                *(f16x4*)&pv[(bh << 14) + (dd << 10) + s0] = vv;
            } else {
                const float sc = (part == 0) ? 0.36067376022224085f : 1.f;
                _Float16* dst = (part == 0) ? pq : pk;
                #pragma unroll
                for (int rr = 0; rr < 4; rr++)
                    dst[(bh * 1024 + s0 + rr) * HD_ + dd] =
                        (_Float16)((acc[fm][fn][rr] + bcol) * sc);
            }
        }
    }
}

// ---------------------------------------------------------------------------
// Out-proj: BM=64, BN=128, 128 blocks; t f32; fused norm1 stats -> pstatA.
// ---------------------------------------------------------------------------
__global__ __launch_bounds__(256)
void gemm_out(const ushort_t* __restrict__ attno, const ushort_t* __restrict__ Wo_t,
              const float* __restrict__ bo, const float* __restrict__ x,
              float* __restrict__ t, float* __restrict__ pstatA)
{
    __shared__ __align__(16) ushort_t As[4][64][8];
    __shared__ __align__(16) ushort_t Bs[4][128][8];
    __shared__ float2 sred[4][128];
    const int tok0 = blockIdx.x * 64;
    const int tid = threadIdx.x;
    const int l = tid & 63, wv = tid >> 6;
    const int lc = l & 15, lg = l >> 4;

    f32x4 acc[8] = {};

    const int arow = tid & 63, akc = tid >> 6;
    const int bn = tid & 127, bj = tid >> 7;
    const ushort_t* ap = attno + (size_t)(tok0 + arow) * D_ + akc * 8;
    const ushort_t* bp = Wo_t + (size_t)bn * D_ + bj * 16;

    for (int k0 = 0; k0 < 128; k0 += 32) {
        *(bf16x8*)As[akc][arow]     = *(const bf16x8*)(ap + k0);
        *(bf16x8*)Bs[bj * 2][bn]     = *(const bf16x8*)(bp + k0);
        *(bf16x8*)Bs[bj * 2 + 1][bn] = *(const bf16x8*)(bp + k0 + 8);
        __syncthreads();
        bf16x8 af = *(const bf16x8*)As[lg][wv * 16 + lc];
        #pragma unroll
        for (int fn = 0; fn < 8; fn++) {
            bf16x8 bf = *(const bf16x8*)Bs[lg][fn * 16 + lc];
            acc[fn] = __builtin_amdgcn_mfma_f32_16x16x32_bf16(af, bf, acc[fn], 0, 0, 0);
        }
        __syncthreads();
    }

    const int bb = tok0 >> 10, c16 = (tok0 >> 6) & 15;
    #pragma unroll
    for (int fn = 0; fn < 8; fn++) {
        const int col = fn * 16 + lc;
        float s = 0.f, q = 0.f;
        #pragma unroll
        for (int rr = 0; rr < 4; rr++) {
            const int row = wv * 16 + lg * 4 + rr;
            const size_t off = (size_t)(tok0 + row) * D_ + col;
            float v = acc[fn][rr] + bo[col] + x[off];
            t[off] = v;
            s += v; q += v * v;
        }
        s += __shfl_xor(s, 16); q += __shfl_xor(q, 16);
        s += __shfl_xor(s, 32); q += __shfl_xor(q, 32);
        if (l < 16) sred[wv][col] = make_float2(s, q);
    }
    __syncthreads();
    if (tid < 128) {
        float2 a0 = sred[0][tid], a1 = sred[1][tid], a2 = sred[2][tid], a3 = sred[3][tid];
        ((float2*)pstatA)[(bb * 16 + c16) * D_ + tid] =
            make_float2(a0.x + a1.x + a2.x + a3.x, a0.y + a1.y + a2.y + a3.y);
    }
}

// ---------------------------------------------------------------------------
// Fully fused MoE: norm1 (from pstatA) + f32 gating + 2 GEMMs, per block
// 64 tokens x 1 expert, grid (128, 4).
// ---------------------------------------------------------------------------
__global__ __launch_bounds__(256)
void moe_fused(const float* __restrict__ t, const float* __restrict__ pstatA,
               const float* __restrict__ n1w, const float* __restrict__ n1b,
               const float* __restrict__ wg,
               const ushort_t* __restrict__ W1t, const ushort_t* __restrict__ W2t,
               const float* __restrict__ b1, const float* __restrict__ b2,
               ushort_t* __restrict__ ypartb)
{
    __shared__ __align__(16) ushort_t As[16][64][8];
    __shared__ __align__(16) ushort_t HS[16][64][8];
    __shared__ float2 sst[128];
    __shared__ float4 glog[4][64];
    __shared__ float garr[64];
    const int tok0 = blockIdx.x * 64, e = blockIdx.y;
    const int tid = threadIdx.x;
    const int l = tid & 63, wv = tid >> 6;
    const int lc = l & 15, lg = l >> 4;
    const int bb = tok0 >> 10;

    if (tid < 128) {
        float sum = 0.f, sq = 0.f;
        const float2* pp = (const float2*)pstatA;
        #pragma unroll 4
        for (int c = 0; c < 16; c++) {
            float2 v = pp[(bb * 16 + c) * D_ + tid];
            sum += v.x; sq += v.y;
        }
        const float invS = 1.f / (float)S_;
        float mu = sum * invS;
        float var = sq * invS - mu * mu;
        sst[tid] = make_float2(mu, rsqrtf(var + 1e-5f));
    }
    __syncthreads();

    {
        const int row = tid & 63, part = tid >> 6;
        const float* src = t + (size_t)(tok0 + row) * D_ + part * 32;
        float4 aa = make_float4(0.f, 0.f, 0.f, 0.f);
        #pragma unroll
        for (int j = 0; j < 4; j++) {
            bf16x8 pk8;
            #pragma unroll
            for (int half = 0; half < 2; half++) {
                float4 v = *(const float4*)(src + j * 8 + half * 4);
                const int db = part * 32 + j * 8 + half * 4;
                float hv[4] = {v.x, v.y, v.z, v.w};
                #pragma unroll
                for (int c = 0; c < 4; c++) {
                    float2 s = sst[db + c];
                    hv[c] = (hv[c] - s.x) * s.y * n1w[db + c] + n1b[db + c];
                    float4 wj = ((const float4*)wg)[db + c];
                    aa.x += hv[c] * wj.x; aa.y += hv[c] * wj.y;
                    aa.z += hv[c] * wj.z; aa.w += hv[c] * wj.w;
                    pk8[half * 4 + c] = (short)f2bf(hv[c]);
                }
            }
            *(bf16x8*)As[part * 4 + j][row] = pk8;
        }
        glog[part][row] = aa;
    }
    __syncthreads();
    if (tid < 64) {
        float4 a0 = glog[0][tid], a1 = glog[1][tid], a2 = glog[2][tid], a3 = glog[3][tid];
        float lv[4] = {a0.x + a1.x + a2.x + a3.x, a0.y + a1.y + a2.y + a3.y,
                       a0.z + a1.z + a2.z + a3.z, a0.w + a1.w + a2.w + a3.w};
        int i0 = 0; float mm0 = lv[0];
        #pragma unroll
        for (int k = 1; k < 4; k++) if (lv[k] > mm0) { mm0 = lv[k]; i0 = k; }
        int i1 = -1; float mm1 = -1e30f;
        #pragma unroll
        for (int k = 0; k < 4; k++) {
            if (k == i0) continue;
            if (lv[k] > mm1) { mm1 = lv[k]; i1 = k; }
        }
        float te = __expf(mm1 - mm0);
        float g0 = 1.f / (1.f + te);
        float g1 = te * g0;
        garr[tid] = (e == i0) ? g0 : (e == i1) ? g1 : 0.f;
    }
    __syncthreads();

    const ushort_t* W1e = W1t + (size_t)e * HFF_ * D_;
    const ushort_t* W2e = W2t + (size_t)e * D_ * HFF_;
    const int col0 = wv * 32 + lc;

    f32x4 acc2[4][2] = {};

    #pragma unroll
    for (int c = 0; c < 4; c++) {
        bf16x8 w1f[4][2], w2f[4][2];
        #pragma unroll
        for (int ks = 0; ks < 4; ks++)
            #pragma unroll
            for (int fn = 0; fn < 2; fn++) {
                w1f[ks][fn] = *(const bf16x8*)&W1e[(size_t)(c * 128 + col0 + fn * 16) * D_ + ks * 32 + lg * 8];
                w2f[ks][fn] = *(const bf16x8*)&W2e[(size_t)(col0 + fn * 16) * HFF_ + c * 128 + ks * 32 + lg * 8];
            }
        f32x4 acc1[4][2] = {};
        #pragma unroll
        for (int ks = 0; ks < 4; ks++) {
            bf16x8 af[4];
            #pragma unroll
            for (int f = 0; f < 4; f++) af[f] = *(const bf16x8*)As[ks * 4 + lg][f * 16 + lc];
            #pragma unroll
            for (int fm = 0; fm < 4; fm++)
                #pragma unroll
                for (int fn = 0; fn < 2; fn++)
                    acc1[fm][fn] = __builtin_amdgcn_mfma_f32_16x16x32_bf16(
                        af[fm], w1f[ks][fn], acc1[fm][fn], 0, 0, 0);
        }
        __syncthreads();
        #pragma unroll
        for (int fm = 0; fm < 4; fm++)
            #pragma unroll
            for (int fn = 0; fn < 2; fn++)
                #pragma unroll
                for (int rr = 0; rr < 4; rr++) {
                    const int row = fm * 16 + lg * 4 + rr;
                    const int col = wv * 32 + fn * 16 + lc;
                    float v = fmaxf(acc1[fm][fn][rr] + b1[e * HFF_ + c * 128 + col], 0.f);
                    HS[col >> 3][row][col & 7] = f2bf(v);
                }
        __syncthreads();
        #pragma unroll
        for (int ks2 = 0; ks2 < 4; ks2++) {
            bf16x8 af[4];
            #pragma unroll
            for (int f = 0; f < 4; f++) af[f] = *(const bf16x8*)HS[ks2 * 4 + lg][f * 16 + lc];
            #pragma unroll
            for (int fm = 0; fm < 4; fm++)
                #pragma unroll
                for (int fn = 0; fn < 2; fn++)
                    acc2[fm][fn] = __builtin_amdgcn_mfma_f32_16x16x32_bf16(
                        af[fm], w2f[ks2][fn], acc2[fm][fn], 0, 0, 0);
        }
    }

    #pragma unroll
    for (int fm = 0; fm < 4; fm++)
        #pragma unroll
        for (int rr = 0; rr < 4; rr++) {
            const int row = fm * 16 + lg * 4 + rr;
            const float g = garr[row];
            #pragma unroll
            for (int fn = 0; fn < 2; fn++) {
                const int d = wv * 32 + fn * 16 + lc;
                ypartb[((size_t)e * NTOK + tok0 + row) * D_ + d] =
                    f2bf(g * (acc2[fm][fn][rr] + b2[e * D_ + d]));
            }
        }
}

// ---------------------------------------------------------------------------
// MFMA flash attention, LDS-staged K/V, 8 waves x 16 q rows (512 threads).
// grid (B*NH, 8). (Round-15 shape — best measured.)
// ---------------------------------------------------------------------------
#define KT_STR 20
#define VT_STR 136

__global__ __launch_bounds__(512)
void attn_mfma(const _Float16* __restrict__ Qb, const _Float16* __restrict__ Kb,
               const _Float16* __restrict__ Vt, ushort_t* __restrict__ attno)
{
    __shared__ __align__(16) _Float16 KT[2][128 * KT_STR];
    __shared__ __align__(16) _Float16 VTs[2][16 * VT_STR];
    const int bh = blockIdx.x;
    const int tid = threadIdx.x;
    const int wv = tid >> 6;
    const int l  = tid & 63;
    const int r = l & 15, g = l >> 4;
    const int g4 = g * 4;
    const int q0 = blockIdx.y * 128 + wv * 16;

    const _Float16* qp = Qb + ((size_t)bh << 14);
    const _Float16* kp = Kb + ((size_t)bh << 14);
    const _Float16* vp = Vt + ((size_t)bh << 14);

    f16x4 qf = *(const f16x4*)&qp[(q0 + r) * HD_ + g4];

    const int krow = tid >> 2, kq = tid & 3;
    const int kofs = krow * KT_STR + kq * 4;
    const _Float16* kg = kp + krow * HD_ + kq * 4;
    const int vrow = tid >> 5, vsc = tid & 31;
    const int vofs = vrow * VT_STR + vsc * 4;
    const _Float16* vg = vp + vrow * 1024 + vsc * 4;

    const int kbase = r * KT_STR + g4;
    const int vbase = r * VT_STR + g4;

    f32x4 o = {};
    float lp = 0.f;

    {
        *(f16x4*)&KT[0][kofs]  = *(const f16x4*)kg;
        *(f16x4*)&VTs[0][vofs] = *(const f16x4*)vg;
    }
    __syncthreads();

    int cur = 0;
    #pragma unroll 1
    for (int t = 0; t < 8; t++) {
        f16x4 kr, vr;
        if (t < 7) {
            kr = *(const f16x4*)(kg + (t + 1) * 2048);
            vr = *(const f16x4*)(vg + (t + 1) * 128);
        }
        const _Float16* KTc = KT[cur];
        const _Float16* VTc = VTs[cur];
        #pragma unroll
        for (int kt = 0; kt < 8; kt++) {
            f16x4 kf = *(const f16x4*)&KTc[kbase + kt * (16 * KT_STR)];
            f16x4 vf = *(const f16x4*)&VTc[vbase + kt * 16];
            f32x4 z = {};
            f32x4 s0 = __builtin_amdgcn_mfma_f32_16x16x16f16(kf, qf, z, 0, 0, 0);
            float p0 = exp2f(s0[0]), p1 = exp2f(s0[1]), p2 = exp2f(s0[2]), p3 = exp2f(s0[3]);
            lp += (p0 + p1) + (p2 + p3);
            f16x4 pf;
            pf[0] = (_Float16)p0; pf[1] = (_Float16)p1;
            pf[2] = (_Float16)p2; pf[3] = (_Float16)p3;
            o = __builtin_amdgcn_mfma_f32_16x16x16f16(vf, pf, o, 0, 0, 0);
        }
        if (t < 7) {
            *(f16x4*)&KT[cur ^ 1][kofs]  = kr;
            *(f16x4*)&VTs[cur ^ 1][vofs] = vr;
        }
        __syncthreads();
        cur ^= 1;
    }

    lp += __shfl_xor(lp, 16);
    lp += __shfl_xor(lp, 32);
    const float inv = 1.f / lp;

    const int b = bh >> 3, h = bh & 7;
    ushort4 out;
    out.x = f2bf(o[0] * inv); out.y = f2bf(o[1] * inv);
    out.z = f2bf(o[2] * inv); out.w = f2bf(o[3] * inv);
    *(ushort4*)&attno[((size_t)(b * S_ + q0 + r)) * D_ + h * HD_ + g4] = out;
}

// ---------------------------------------------------------------------------
// Reduce: yh = norm1(t) + sum_e ypartb[e]. grid (B, 64) x 256 threads:
// block = 16 tokens, thread = (token-pair, d), 8 s-iterations -> 4x TLP of
// the old (B,32)x128 version. norm2 partials -> pstatB[64 chunks].
// ---------------------------------------------------------------------------
__global__ __launch_bounds__(256)
void moe_reduce_stats(const ushort_t* __restrict__ ypartb, const float* __restrict__ t,
                      const float* __restrict__ pstatA,
                      const float* __restrict__ n1w, const float* __restrict__ n1b,
                      ushort_t* __restrict__ yhb, float* __restrict__ pstatB)
{
    __shared__ float2 sred[2][128];
    const int bb = blockIdx.x, chunk = blockIdx.y;   // 64 chunks of 16 tokens
    const int d = threadIdx.x & 127, tp = threadIdx.x >> 7;  // token-pair half

    float sum0 = 0.f, sq0 = 0.f;
    const float2* pp = (const float2*)pstatA;
    #pragma unroll 4
    for (int c = 0; c < 16; c++) {
        float2 v = pp[(bb * 16 + c) * D_ + d];
        sum0 += v.x; sq0 += v.y;
    }
    const float invS = 1.f / (float)S_;
    const float mu = sum0 * invS;
    const float rstd = rsqrtf(sq0 * invS - mu * mu + 1e-5f);
    const float wd = n1w[d], bd = n1b[d];

    float sum = 0.f, sq = 0.f;
    #pragma unroll
    for (int s = 0; s < 8; s++) {
        const int tok = bb * 1024 + chunk * 16 + tp * 8 + s;
        const size_t off = (size_t)tok * D_ + d;
        float hv = (t[off] - mu) * rstd * wd + bd;
        float v = hv
                + bf2f(ypartb[off])
                + bf2f(ypartb[(size_t)1 * NTOK * D_ + off])
                + bf2f(ypartb[(size_t)2 * NTOK * D_ + off])
                + bf2f(ypartb[(size_t)3 * NTOK * D_ + off]);
        yhb[off] = f2bf(v);
        sum += v; sq += v * v;
    }
    sred[tp][d] = make_float2(sum, sq);
    __syncthreads();
    if (threadIdx.x < 128) {
        float2 a = sred[0][d], b2v = sred[1][d];
        ((float2*)pstatB)[(bb * 64 + chunk) * D_ + d] =
            make_float2(a.x + b2v.x, a.y + b2v.y);
    }
}

// ---------------------------------------------------------------------------
// Final norm apply with fused stats combine from pstatB (64 chunks).
// ---------------------------------------------------------------------------
__global__ __launch_bounds__(256)
void in_apply_final(const ushort_t* __restrict__ a, const float* __restrict__ pstatB,
                    const float* __restrict__ w, const float* __restrict__ bias,
                    float* __restrict__ outp)
{
    __shared__ float2 sst[128];
    const int tid = threadIdx.x;
    const int bb = (int)((blockIdx.x * 8) >> 10);
    if (tid < 128) {
        float sum = 0.f, sq = 0.f;
        const float2* pp = (const float2*)pstatB;
        #pragma unroll 4
        for (int c = 0; c < 64; c++) {
            float2 v = pp[(bb * 64 + c) * D_ + tid];
            sum += v.x; sq += v.y;
        }
        const float invS = 1.f / (float)S_;
        float mu = sum * invS;
        float var = sq * invS - mu * mu;
        sst[tid] = make_float2(mu, rsqrtf(var + 1e-5f));
    }
    __syncthreads();

    size_t i4 = (size_t)blockIdx.x * 256 + tid;
    int d0 = (tid & 31) * 4;
    ushort4 u = ((const ushort4*)a)[i4];
    float4 v = make_float4(bf2f(u.x), bf2f(u.y), bf2f(u.z), bf2f(u.w));
    float2 s0 = sst[d0 + 0];
    float2 s1 = sst[d0 + 1];
    float2 s2 = sst[d0 + 2];
    float2 s3 = sst[d0 + 3];
    float4 r;
    r.x = (v.x - s0.x) * s0.y * w[d0 + 0] + bias[d0 + 0];
    r.y = (v.y - s1.x) * s1.y * w[d0 + 1] + bias[d0 + 1];
    r.z = (v.z - s2.x) * s2.y * w[d0 + 2] + bias[d0 + 2];
    r.w = (v.w - s3.x) * s3.y * w[d0 + 3] + bias[d0 + 3];
    ((float4*)outp)[i4] = r;
}

// ---------------------------------------------------------------------------
// Launch (7 dispatches)
// ---------------------------------------------------------------------------
extern "C" void kernel_launch(void* const* d_in, const int* in_sizes, int n_in,
                              void* d_out, int out_size, void* d_ws, size_t ws_size,
                              hipStream_t stream)
{
    const float* x    = (const float*)d_in[0];
    const float* Wqkv = (const float*)d_in[1];
    const float* bqkv = (const float*)d_in[2];
    const float* Wo   = (const float*)d_in[3];
    const float* bo   = (const float*)d_in[4];
    const float* n1w  = (const float*)d_in[5];
    const float* n1b  = (const float*)d_in[6];
    const float* n2w  = (const float*)d_in[7];
    const float* n2b  = (const float*)d_in[8];
    const float* wg   = (const float*)d_in[9];
    const float* W1   = (const float*)d_in[10];
    const float* b1   = (const float*)d_in[11];
    const float* W2   = (const float*)d_in[12];
    const float* b2   = (const float*)d_in[13];

    // Workspace layout (~28 MB)
    char* ws = (char*)d_ws;
    _Float16* Qb     = (_Float16*)(ws);                          // [0,2M)
    _Float16* Kb     = (_Float16*)(ws + (2u << 20));             // [2,4M)
    _Float16* Vt     = (_Float16*)(ws + (4u << 20));             // [4,6M)
    ushort_t* attno  = (ushort_t*)(ws + (6u << 20));             // [6,8M)
    float*    t      = (float*)(ws + (8u << 20));                // [8,12M)
    ushort_t* ypartb = (ushort_t*)(ws + (14u << 20));            // [14,22M)
    ushort_t* yhb    = (ushort_t*)(ws + (22u << 20));            // [22,24M)
    char*     wbase  = ws + (26u << 20);
    ushort_t* Wqkv_t = (ushort_t*)(wbase);                       // 96 KB
    ushort_t* Wo_t   = (ushort_t*)(wbase + (128u << 10));        // 32 KB
    ushort_t* W1t    = (ushort_t*)(wbase + (192u << 10));        // 512 KB
    ushort_t* W2t    = (ushort_t*)(wbase + (704u << 10));        // 512 KB
    float*    pstatA = (float*)(wbase + (1216u << 10));          // 128 KB
    float*    pstatB = (float*)(wbase + (1344u << 10));          // 512 KB

    dim3 blk(256);

    prep<<<dim3(1024, 4), blk, 0, stream>>>(Wqkv, Wo, W1, W2,
                                            Wqkv_t, Wo_t, W1t, W2t);
    gemm_qkv<<<dim3(64, 3), blk, 0, stream>>>(x, Wqkv_t, bqkv, Qb, Kb, Vt);
    attn_mfma<<<dim3(64, 8), dim3(512), 0, stream>>>(Qb, Kb, Vt, attno);
    gemm_out<<<dim3(128), blk, 0, stream>>>(attno, Wo_t, bo, x, t, pstatA);
    moe_fused<<<dim3(128, 4), blk, 0, stream>>>(t, pstatA, n1w, n1b, wg,
                                                W1t, W2t, b1, b2, ypartb);
    moe_reduce_stats<<<dim3(B_, 64), blk, 0, stream>>>(ypartb, t, pstatA,
                                                       n1w, n1b, yhb, pstatB);
    in_apply_final<<<dim3(1024), blk, 0, stream>>>(yhb, pstatB, n2w, n2b,
                                                   (float*)d_out);
}